// Round 23
// baseline (323.359 us; speedup 1.0000x reference)
//
#include <hip/hip_runtime.h>
#include <math.h>

// ---------------- ws byte offsets ----------------
#define B_CTXC   0          // single summed ctx [2][8][32][32] f32 = 65536 B
#define B_ZP     524288     // [2][256] f32
#define B_COLS   526336     // [2][512] f32
#define B_HIGH2  530432     // [2][256] f32
#define B_CONSTD 532480     // [2][2] f32 (+pad)
#define B_BIASO  532544     // [512] f32
#define B_CPP    534592     // [256] f32 (c'')
#define B_CTXT   535616     // [2][8] x 2 tiles x 1KB bf16, fragment-linear
#define B_WDD    568384     // [2][256] f32
#define B_WDX    570432     // [2][512] f32
#define B_WL     574528     // [256][512] f32 (W_L'')
#define B_WBIG   1098816    // 33 tiles x 16KB bf16, fragment-linear
#define B_WKV    1639488    // 32 tiles x 16KB bf16, fragment-linear
#define B_WR     2163776    // 32 tiles x 8KB bf16, fragment-linear
#define B_PW1T   2425920    // [512][512] f32 transposed
#define B_PW2T   3474496    // [512][256] f32 transposed
#define B_D1BT   3998784    // [256][256] f32 transposed
// d_out scratch (before k3 overwrites): [1024][8192] u32 ctx partials at u32
// index 0 (32MB), [1024][1536] f32 red partials at float offset 8388608.

typedef __attribute__((ext_vector_type(8))) short bf16x8;
typedef __attribute__((ext_vector_type(4))) float f32x4;

#define MFMA(a, b, c) __builtin_amdgcn_mfma_f32_16x16x32_bf16(a, b, c, 0, 0, 0)
#define EVSWZ(row) ((((row) >> 1) & 3) << 4)

__device__ inline unsigned f2bfu(float f) {
  unsigned u = __float_as_uint(f);
  return (u + 0x7FFFu + ((u >> 16) & 1u)) >> 16;
}
__device__ inline unsigned pack2(float a, float b) { return f2bfu(a) | (f2bfu(b) << 16); }

// softmax over 32 head-channels -> 4 packed bf16x2 words
__device__ inline void softmax_pack(f32x4 a0, f32x4 a1, const float* __restrict__ bq,
                                    int hh, int g, unsigned o[4]) {
  float q[8], e[8];
  float mx = -1e30f;
#pragma unroll
  for (int r = 0; r < 4; ++r) {
    q[r] = a0[r] + bq[hh * 32 + g * 4 + r];
    q[4 + r] = a1[r] + bq[hh * 32 + 16 + g * 4 + r];
    mx = fmaxf(mx, fmaxf(q[r], q[4 + r]));
  }
  mx = fmaxf(mx, __shfl_xor(mx, 16, 64));
  mx = fmaxf(mx, __shfl_xor(mx, 32, 64));
  float sm = 0.f;
#pragma unroll
  for (int r = 0; r < 8; ++r) { e[r] = __expf(q[r] - mx); sm += e[r]; }
  sm += __shfl_xor(sm, 16, 64);
  sm += __shfl_xor(sm, 32, 64);
  float inv = 1.f / sm;
  o[0] = pack2(e[0] * inv, e[1] * inv); o[1] = pack2(e[2] * inv, e[3] * inv);
  o[2] = pack2(e[4] * inv, e[5] * inv); o[3] = pack2(e[6] * inv, e[7] * inv);
}

// ---------------- kFuse1: blocks 0-255 = kW1; blocks 256+ = independent packs ----------------
__global__ __launch_bounds__(512) void kFuse1(
    const float* __restrict__ a1, const float* __restrict__ abn1,
    const float* __restrict__ a2, const float* __restrict__ abn2,
    const float* __restrict__ wq, const float* __restrict__ wk, const float* __restrict__ wv,
    const float* __restrict__ wr, const float* __restrict__ pw1, const float* __restrict__ pw2,
    const float* __restrict__ d1, char* __restrict__ wsb) {
  __shared__ float S1[512], F1[512], redu[512];
  const int t = threadIdx.x;
  float* wsf = (float*)wsb;
  unsigned short* u16 = (unsigned short*)wsb;
  if (blockIdx.x < 256) {
    const int o = blockIdx.x;
    {
      float gg = abn1[t], be = abn1[512 + t], mn = abn1[1024 + t], va = abn1[1536 + t];
      float s = gg * rsqrtf(va + 1e-5f);
      S1[t] = s; F1[t] = be - mn * s;
    }
    float g2 = abn2[o], be2 = abn2[256 + o], mn2 = abn2[512 + o], va2 = abn2[768 + o];
    float s2 = g2 * rsqrtf(va2 + 1e-5f);
    float f2v = be2 - mn2 * s2;
    __syncthreads();
    float acc = 0.f;
    const float* a2r = a2 + o * 512;
    for (int m = 0; m < 512; ++m) acc = fmaf(a2r[m] * S1[m], a1[m * 512 + t], acc);
    wsf[(B_WL / 4) + o * 512 + t] = s2 * acc;
    redu[t] = a2r[t] * F1[t];
    __syncthreads();
    for (int sft = 256; sft >= 1; sft >>= 1) {
      if (t < sft) redu[t] += redu[t + sft];
      __syncthreads();
    }
    if (t == 0) wsf[(B_CPP / 4) + o] = s2 * redu[0] + f2v;
    return;
  }
  int i = (blockIdx.x - 256) * 512 + t;
  if (i < 131072) {  // Wbig tiles 0-15 (wq rows)
    int T = i >> 13, r = i & 8191;
    int ks = r >> 9, l = (r >> 3) & 63, j = r & 7;
    int row = T * 16 + (l & 15);
    int col = ks * 32 + (l >> 4) * 8 + j;
    u16[(B_WBIG / 2) + i] = (unsigned short)f2bfu(wq[row * 512 + col]);
    return;
  }
  i -= 131072;
  if (i < 262144) {  // Wkv: 32 tiles, K=512
    int T = i >> 13, r = i & 8191;
    int ks = r >> 9, l = (r >> 3) & 63, j = r & 7;
    int row = T * 16 + (l & 15);
    int col = ks * 32 + (l >> 4) * 8 + j;
    float v = row < 256 ? wk[row * 512 + col] : wv[(row - 256) * 512 + col];
    u16[(B_WKV / 2) + i] = (unsigned short)f2bfu(v);
    return;
  }
  i -= 262144;
  if (i < 131072) {  // WR: 32 tiles, K=256
    int T = i >> 12, r = i & 4095;
    int ks = r >> 9, l = (r >> 3) & 63, j = r & 7;
    int row = T * 16 + (l & 15);
    int col = ks * 32 + (l >> 4) * 8 + j;
    u16[(B_WR / 2) + i] = (unsigned short)f2bfu(wr[row * 256 + col]);
    return;
  }
  i -= 131072;
  if (i < 262144) { int o = i >> 9, c = i & 511; wsf[(B_PW1T / 4) + c * 512 + o] = pw1[i]; return; }
  i -= 262144;
  if (i < 131072) { int o = i >> 9, c = i & 511; wsf[(B_PW2T / 4) + c * 256 + o] = pw2[i]; return; }
  i -= 131072;
  if (i < 65536) { int o = i >> 8, v = i & 255; wsf[(B_D1BT / 4) + v * 256 + o] = d1[o * 512 + 256 + v]; }
}

// ---------------- kW2: W_dd, W_dx — 8 blocks x 64 columns ----------------
__global__ __launch_bounds__(512) void kW2(
    const float* __restrict__ d1, const float* __restrict__ dbn1,
    const float* __restrict__ d2, char* __restrict__ wsb) {
  __shared__ float SD[256], WDDl[512], part[512];
  const int t = threadIdx.x, blk = blockIdx.x;
  float* wsf = (float*)wsb;
  if (t < 256) {
    float gg = dbn1[t], va = dbn1[768 + t];
    SD[t] = gg * rsqrtf(va + 1e-5f);
  }
  __syncthreads();
  {
    int j = t >> 8, v = t & 255;
    float acc = 0.f;
    for (int o = 0; o < 256; ++o) acc = fmaf(d2[j * 256 + o] * SD[o], d1[o * 512 + v], acc);
    WDDl[t] = acc;
    if (blk == 0) wsf[(B_WDD / 4) + t] = acc;
  }
  __syncthreads();
  const int cl = t & 63, vp = t >> 6;
  const int c = blk * 64 + cl;
  float acc0 = 0.f, acc1 = 0.f;
  for (int v = vp * 32; v < vp * 32 + 32; ++v) {
    float wl = wsf[(B_WL / 4) + v * 512 + c];
    acc0 = fmaf(WDDl[v], wl, acc0);
    acc1 = fmaf(WDDl[256 + v], wl, acc1);
  }
  part[t] = acc0;
  __syncthreads();
  if (t < 64) {
    float s = 0.f;
#pragma unroll
    for (int p2 = 0; p2 < 8; ++p2) s += part[p2 * 64 + t];
    wsf[(B_WDX / 4) + blk * 64 + t] = s;
  }
  __syncthreads();
  part[t] = acc1;
  __syncthreads();
  if (t < 64) {
    float s = 0.f;
#pragma unroll
    for (int p2 = 0; p2 < 8; ++p2) s += part[p2 * 64 + t];
    wsf[(B_WDX / 4) + 512 + blk * 64 + t] = s;
  }
}

// ---------------- kPackB: Wbig tiles 16-32 (depend on W_L / WDX) ----------------
__global__ __launch_bounds__(512) void kPackB(char* __restrict__ wsb) {
  float* wsf = (float*)wsb;
  unsigned short* u16 = (unsigned short*)wsb;
  int i = blockIdx.x * 512 + threadIdx.x + 131072;  // Wbig element index, tiles 16..32
  if (i >= 270336) return;
  int T = i >> 13, r = i & 8191;
  int ks = r >> 9, l = (r >> 3) & 63, j = r & 7;
  int row = T * 16 + (l & 15);
  int col = ks * 32 + (l >> 4) * 8 + j;
  float v;
  if (row < 512) v = wsf[(B_WL / 4) + (row - 256) * 512 + col];
  else if (row < 514) v = wsf[(B_WDX / 4) + (row - 512) * 512 + col];
  else v = 0.f;
  u16[(B_WBIG / 2) + i] = (unsigned short)f2bfu(v);
}

// ---------------- k1: LDS-overlaid, NT-streaming x/y ----------------
__global__ __launch_bounds__(1024, 2) void k1_reduce(
    const float* __restrict__ x, const float* __restrict__ y,
    const float* __restrict__ bk, const float* __restrict__ bv,
    const char* __restrict__ wsb, float* __restrict__ outp) {
  __shared__ __align__(16) unsigned char XYl[65536];  // Xl|Yl -> PS -> el/vl
  __shared__ float Red[1536];
  unsigned char* Xl = XYl;
  unsigned char* Yl = XYl + 32768;
  float* PSf = (float*)XYl;
  unsigned char* elx = XYl;
  unsigned char* ely = XYl + 16384;
  unsigned char* vlx = XYl + 32768;
  unsigned char* vly = XYl + 49152;
  const int t = threadIdx.x;
  const int tw = t >> 6, lo16 = t & 15, g = (t >> 4) & 3, l = t & 63;
  const char* Wkv = wsb + B_WKV;

  if (t < 512) Red[t] = 0.f;
  float csum[2][8];
#pragma unroll
  for (int b2 = 0; b2 < 2; ++b2)
#pragma unroll
    for (int i = 0; i < 8; ++i) csum[b2][i] = 0.f;
  const int n0 = blockIdx.x * 32;
  const int bbase0 = lo16 * 1024 + g * 16;
  const int bbase1 = bbase0 + 16384;
  const int bswz = (lo16 & 7) << 4;
  const int pp0 = lo16, pp1 = 16 + lo16;

#pragma unroll
  for (int r = 0; r < 2; ++r) {
    int chunk = r * 1024 + t;
    int prow = chunk >> 6, j = chunk & 63;
    const f32x4* gx = (const f32x4*)(x + (size_t)(n0 + prow) * 512 + j * 8);
    const f32x4* gy = (const f32x4*)(y + (size_t)(n0 + prow) * 512 + j * 8);
    f32x4 x0 = __builtin_nontemporal_load(gx);
    f32x4 x1 = __builtin_nontemporal_load(gx + 1);
    f32x4 y0 = __builtin_nontemporal_load(gy);
    f32x4 y1 = __builtin_nontemporal_load(gy + 1);
#pragma unroll
    for (int q2 = 0; q2 < 4; ++q2) {
      csum[0][q2] += x0[q2]; csum[0][4 + q2] += x1[q2];
      csum[1][q2] += y0[q2]; csum[1][4 + q2] += y1[q2];
    }
    int byte = (prow * 1024 + j * 16) ^ ((prow & 7) << 4);
    uint4 pk;
    pk.x = pack2(x0[0], x0[1]); pk.y = pack2(x0[2], x0[3]);
    pk.z = pack2(x1[0], x1[1]); pk.w = pack2(x1[2], x1[3]);
    *(uint4*)(Xl + byte) = pk;
    pk.x = pack2(y0[0], y0[1]); pk.y = pack2(y0[2], y0[3]);
    pk.z = pack2(y1[0], y1[1]); pk.w = pack2(y1[2], y1[3]);
    *(uint4*)(Yl + byte) = pk;
  }
  __syncthreads();  // (A)

  f32x4 ax0p0 = {0,0,0,0}, ax0p1 = {0,0,0,0}, ay0p0 = {0,0,0,0}, ay0p1 = {0,0,0,0};
  f32x4 ax1p0 = {0,0,0,0}, ax1p1 = {0,0,0,0}, ay1p0 = {0,0,0,0}, ay1p1 = {0,0,0,0};
  {
    int t0 = tw * 2;
    const char* ap = Wkv + t0 * 16384 + l * 16;
    __builtin_amdgcn_s_setprio(1);
#pragma unroll
    for (int ks = 0; ks < 16; ++ks) {
      bf16x8 bx0 = *(const bf16x8*)(Xl + ((bbase0 + ks * 64) ^ bswz));
      bf16x8 bx1 = *(const bf16x8*)(Xl + ((bbase1 + ks * 64) ^ bswz));
      bf16x8 by0 = *(const bf16x8*)(Yl + ((bbase0 + ks * 64) ^ bswz));
      bf16x8 by1 = *(const bf16x8*)(Yl + ((bbase1 + ks * 64) ^ bswz));
      bf16x8 af0 = *(const bf16x8*)(ap + ks * 1024);
      bf16x8 af1 = *(const bf16x8*)(ap + 16384 + ks * 1024);
      ax0p0 = MFMA(af0, bx0, ax0p0); ax0p1 = MFMA(af0, bx1, ax0p1);
      ay0p0 = MFMA(af0, by0, ay0p0); ay0p1 = MFMA(af0, by1, ay0p1);
      ax1p0 = MFMA(af1, bx0, ax1p0); ax1p1 = MFMA(af1, bx1, ax1p1);
      ay1p0 = MFMA(af1, by0, ay1p0); ay1p1 = MFMA(af1, by1, ay1p1);
    }
    __builtin_amdgcn_s_setprio(0);
  }
  float ex0[2][4], ex1[2][4], ey0[2][4], ey1[2][4];
  if (tw < 8) {
    int t0 = tw * 2, t1 = t0 + 1;
#pragma unroll
    for (int pt2 = 0; pt2 < 2; ++pt2) {
      f32x4 Ax0 = pt2 ? ax0p1 : ax0p0, Ax1 = pt2 ? ax1p1 : ax1p0;
      f32x4 Ay0 = pt2 ? ay0p1 : ay0p0, Ay1 = pt2 ? ay1p1 : ay1p0;
#pragma unroll
      for (int r = 0; r < 4; ++r) {
        float bk0 = bk[t0 * 16 + g * 4 + r], bk1 = bk[t1 * 16 + g * 4 + r];
        ex0[pt2][r] = __expf(Ax0[r] + bk0); ey0[pt2][r] = __expf(Ay0[r] + bk0);
        ex1[pt2][r] = __expf(Ax1[r] + bk1); ey1[pt2][r] = __expf(Ay1[r] + bk1);
      }
#pragma unroll
      for (int r = 0; r < 4; ++r) {
        float v0 = ex0[pt2][r], v1 = ex1[pt2][r], v2 = ey0[pt2][r], v3 = ey1[pt2][r];
        for (int m = 8; m >= 1; m >>= 1) {
          v0 += __shfl_xor(v0, m, 16); v1 += __shfl_xor(v1, m, 16);
          v2 += __shfl_xor(v2, m, 16); v3 += __shfl_xor(v3, m, 16);
        }
        if (lo16 == 0) {
          atomicAdd(&Red[t0 * 16 + g * 4 + r], v0);
          atomicAdd(&Red[t1 * 16 + g * 4 + r], v1);
          atomicAdd(&Red[256 + t0 * 16 + g * 4 + r], v2);
          atomicAdd(&Red[256 + t1 * 16 + g * 4 + r], v3);
        }
      }
    }
  }
  __syncthreads();  // (B)

#pragma unroll
  for (int b = 0; b < 2; ++b)
#pragma unroll
    for (int i = 0; i < 8; ++i) PSf[t * 16 + b * 8 + i] = csum[b][i];
  __syncthreads();  // (C)
  {
    int s = t, b = s >> 9, ch = s & 511, tlow = ch >> 3, ii = ch & 7;
    float sum = 0.f;
#pragma unroll
    for (int w2 = 0; w2 < 16; ++w2) sum += PSf[(w2 * 64 + tlow) * 16 + b * 8 + ii];
    Red[512 + s] = sum;
  }
  __syncthreads();  // (D)

  if (tw < 8) {
    int t0 = tw * 2, t1 = t0 + 1;
#pragma unroll
    for (int pt2 = 0; pt2 < 2; ++pt2) {
      int pp = pt2 ? pp1 : pp0;
#pragma unroll
      for (int r = 0; r < 4; ++r) {
        int row0 = t0 * 16 + g * 4 + r;
        int row1 = t1 * 16 + g * 4 + r;
        int a0 = (row0 * 64 + pp * 2) ^ EVSWZ(row0);
        int a1 = (row1 * 64 + pp * 2) ^ EVSWZ(row1);
        *(unsigned short*)(elx + a0) = (unsigned short)f2bfu(ex0[pt2][r]);
        *(unsigned short*)(elx + a1) = (unsigned short)f2bfu(ex1[pt2][r]);
        *(unsigned short*)(ely + a0) = (unsigned short)f2bfu(ey0[pt2][r]);
        *(unsigned short*)(ely + a1) = (unsigned short)f2bfu(ey1[pt2][r]);
      }
    }
  } else {
    int t0 = tw * 2, t1 = t0 + 1;
#pragma unroll
    for (int pt2 = 0; pt2 < 2; ++pt2) {
      f32x4 Ax0 = pt2 ? ax0p1 : ax0p0, Ax1 = pt2 ? ax1p1 : ax1p0;
      f32x4 Ay0 = pt2 ? ay0p1 : ay0p0, Ay1 = pt2 ? ay1p1 : ay1p0;
      int pp = pt2 ? pp1 : pp0;
#pragma unroll
      for (int r = 0; r < 4; ++r) {
        int row0 = (t0 - 16) * 16 + g * 4 + r;
        int row1 = (t1 - 16) * 16 + g * 4 + r;
        float bv0 = bv[row0], bv1 = bv[row1];
        int a0 = (row0 * 64 + pp * 2) ^ EVSWZ(row0);
        int a1 = (row1 * 64 + pp * 2) ^ EVSWZ(row1);
        *(unsigned short*)(vlx + a0) = (unsigned short)f2bfu(Ax0[r] + bv0);
        *(unsigned short*)(vlx + a1) = (unsigned short)f2bfu(Ax1[r] + bv1);
        *(unsigned short*)(vly + a0) = (unsigned short)f2bfu(Ay0[r] + bv0);
        *(unsigned short*)(vly + a1) = (unsigned short)f2bfu(Ay1[r] + bv1);
      }
    }
  }
  __syncthreads();  // (E)

  {
    const int h2 = tw & 7, bsel = tw >> 3;
    const unsigned char* el = bsel ? ely : elx;
    const unsigned char* vl = bsel ? vly : vlx;
    unsigned* ctxp = (unsigned*)outp + (size_t)blockIdx.x * 8192;
#pragma unroll
    for (int m = 0; m < 2; ++m) {
      int rowe = h2 * 32 + m * 16 + lo16;
      bf16x8 ea = *(const bf16x8*)(el + ((rowe * 64 + g * 16) ^ EVSWZ(rowe)));
      f32x4 c0 = {0.f, 0.f, 0.f, 0.f}, c1 = {0.f, 0.f, 0.f, 0.f};
      {
        int rowv = h2 * 32 + lo16;
        bf16x8 vb = *(const bf16x8*)(vl + ((rowv * 64 + g * 16) ^ EVSWZ(rowv)));
        c0 = MFMA(ea, vb, c0);
      }
      {
        int rowv = h2 * 32 + 16 + lo16;
        bf16x8 vb = *(const bf16x8*)(vl + ((rowv * 64 + g * 16) ^ EVSWZ(rowv)));
        c1 = MFMA(ea, vb, c1);
      }
#pragma unroll
      for (int r = 0; r < 4; ++r)
        __builtin_nontemporal_store(pack2(c0[r], c1[r]),
            &ctxp[((bsel * 2 + m) * 4 + r) * 512 + h2 * 64 + l]);
    }
    float* redp = outp + 8388608 + blockIdx.x * 1536;
    for (int i = t; i < 1536; i += 1024) __builtin_nontemporal_store(Red[i], &redp[i]);
  }
}

// ---------------- k1b: tree-reduce (128 ctx + 96 red blocks) ----------------
__global__ __launch_bounds__(512) void k1b(const float* __restrict__ outp, char* __restrict__ wsb) {
  __shared__ float R[512];
  const int t = threadIdx.x, blk = blockIdx.x;
  float* wsf = (float*)wsb;
  if (blk < 128) {  // ctx: 64 slots per block, 8 partial-sum lanes each
    int sl = t & 63, part = t >> 6;  // part 0..7
    int slot = blk * 64 + sl;
    const unsigned* p = (const unsigned*)outp;
    float s0 = 0.f, s1 = 0.f;
    for (int c = part * 128; c < part * 128 + 128; ++c) {
      unsigned wv = __builtin_nontemporal_load(&p[(size_t)c * 8192 + slot]);
      s0 += __uint_as_float(wv << 16);
      s1 += __uint_as_float(wv & 0xffff0000u);
    }
    R[sl * 8 + part] = s0;
    __syncthreads();
    float sum0 = 0.f;
#pragma unroll
    for (int p2 = 0; p2 < 8; ++p2) sum0 += R[sl * 8 + p2];
    __syncthreads();
    R[sl * 8 + part] = s1;
    __syncthreads();
    float sum1 = 0.f;
#pragma unroll
    for (int p2 = 0; p2 < 8; ++p2) sum1 += R[sl * 8 + p2];
    if (part == 0) {
      int t_ = slot & 511, bmr = slot >> 9;
      int r = bmr & 3, m = (bmr >> 2) & 1, b = bmr >> 3;
      int h = t_ >> 6, g = (t_ >> 4) & 3, lo16 = t_ & 15;
      int klocal = m * 16 + g * 4 + r;
      int base = ((b * 8 + h) * 32 + klocal) * 32;
      wsf[(B_CTXC / 4) + base + lo16] = sum0;
      wsf[(B_CTXC / 4) + base + 16 + lo16] = sum1;
    }
  } else {  // red: 96 blocks x 16 slots, 32-way copy split
    int sj = t & 15, part = t >> 4;
    int slot = (blk - 128) * 16 + sj;
    const float* rp = outp + 8388608;
    float s = 0.f;
    for (int cc = part * 32; cc < part * 32 + 32; ++cc)
      s += __builtin_nontemporal_load(&rp[(size_t)cc * 1536 + slot]);
    R[t] = s;
    __syncthreads();
    if (t < 16) {
      float sum = 0.f;
#pragma unroll
      for (int p2 = 0; p2 < 32; ++p2) sum += R[t + p2 * 16];
      int j = (blk - 128) * 16 + t;
      if (j < 512) wsf[(B_ZP / 4) + j] = sum;
      else wsf[(B_COLS / 4) + (j - 512)] = sum;
    }
  }
}

// ---------------- k2: blocks 0-31 ctx normalize; block 32 pool chain ----------------
__global__ __launch_bounds__(512) void k2_finalize(
    const float* __restrict__ pbn1, const float* __restrict__ pbn2,
    const float* __restrict__ dbn1, const float* __restrict__ d2,
    const float* __restrict__ ea_br, char* __restrict__ wsb) {
  __shared__ float HI[1024], H1[1024], H2l[512], VB[512], slot[4];
  const int t = threadIdx.x;
  float* wsf = (float*)wsb;
  unsigned short* u16 = (unsigned short*)wsb;
  if (blockIdx.x < 32) {
    int idx = blockIdx.x * 512 + t;
    float s = wsf[(B_CTXC / 4) + idx];
    int v = idx & 31, row = idx >> 5;
    int b = row >> 8, kr = row & 255;
    int hh = kr >> 5, kh = kr & 31;
    float val = s / wsf[(B_ZP / 4) + b * 256 + kr];
    int m = v >> 4;
    int lane = (v & 15) + ((kh >> 3) << 4);
    int j = kh & 7;
    u16[(B_CTXT / 2) + (((b * 8 + hh) * 2 + m) << 9) + lane * 8 + j] = (unsigned short)f2bfu(val);
    return;
  }
  if (t < 4) slot[t] = 0.f;
  for (int idx = t; idx < 1024; idx += 512) HI[idx] = wsf[(B_COLS / 4) + idx] * (1.f / 32768.f);
  __syncthreads();
  {
    int o = t;
    float gg = pbn1[o], be = pbn1[512 + o], mn = pbn1[1024 + o], va = pbn1[1536 + o];
    float sc = gg * rsqrtf(va + 1e-5f), sh = be - mn * sc;
    for (int b = 0; b < 2; ++b) {
      float acc = 0.f;
      for (int c = 0; c < 512; ++c) acc = fmaf(wsf[(B_PW1T / 4) + c * 512 + o], HI[b * 512 + c], acc);
      H1[b * 512 + o] = acc * sc + sh;
    }
  }
  __syncthreads();
  if (t < 256) {
    int o = t;
    float gg = pbn2[o], be = pbn2[256 + o], mn = pbn2[512 + o], va = pbn2[768 + o];
    float sc = gg * rsqrtf(va + 1e-5f), sh = be - mn * sc;
    for (int b = 0; b < 2; ++b) {
      float acc = 0.f;
      for (int c = 0; c < 512; ++c) acc = fmaf(wsf[(B_PW2T / 4) + c * 256 + o], H1[b * 512 + c], acc);
      float vv = acc * sc + sh;
      H2l[b * 256 + o] = vv;
      wsf[(B_HIGH2 / 4) + b * 256 + o] = vv;
    }
  }
  __syncthreads();
  if (t < 256) {
    int o = t;
    float gg = dbn1[o], be = dbn1[256 + o], mn = dbn1[512 + o], va = dbn1[768 + o];
    float sd = gg * rsqrtf(va + 1e-5f), fd = be - mn * sd;
    for (int b = 0; b < 2; ++b) {
      float acc = 0.f;
      for (int v = 0; v < 256; ++v) acc = fmaf(wsf[(B_D1BT / 4) + v * 256 + o], H2l[b * 256 + v], acc);
      VB[b * 256 + o] = sd * acc + fd;
    }
  }
  __syncthreads();
  if (t < 256) {
    int o = t;
    for (int b = 0; b < 2; ++b)
      for (int j = 0; j < 2; ++j) atomicAdd(&slot[b * 2 + j], d2[j * 256 + o] * VB[b * 256 + o]);
    float cp = wsf[(B_CPP / 4) + o];
    for (int j = 0; j < 2; ++j) {
      float w = wsf[(B_WDD / 4) + j * 256 + o] * cp;
      atomicAdd(&slot[0 + j], w);
      atomicAdd(&slot[2 + j], w);
    }
  }
  __syncthreads();
  if (t < 4) wsf[(B_CONSTD / 4) + t] = slot[t];
  {
    int o = t;
    float bb = 0.5f * ea_br[o];
    if (o >= 256) bb += 0.5f * wsf[(B_CPP / 4) + o - 256];
    wsf[(B_BIASO / 4) + o] = bb;
  }
}

// ---------------- k3: 16-position blocks, 2 blocks/CU; NT-streaming x/y + output ----------------
__global__ __launch_bounds__(1024, 8) void k3_main(
    const float* __restrict__ x, const float* __restrict__ y,
    const float* __restrict__ bq, const char* __restrict__ wsb,
    float* __restrict__ out) {
  __shared__ __align__(16) unsigned char Xl[16384];
  __shared__ __align__(16) unsigned char Yl[16384];
  __shared__ __align__(16) unsigned char ACCb[32768];  // f32 [16 pos][512 ch], swizzled
  __shared__ __align__(16) unsigned char Ql[8192];     // 1 slab
  __shared__ float wgtl[32];  // [b][pos16]
  const int t = threadIdx.x;
  const int tw = t >> 6, lo16 = t & 15, g = (t >> 4) & 3, l = t & 63;
  const int n0 = blockIdx.x * 16;
  const char* Wbig = wsb + B_WBIG;
  const char* WRp = wsb + B_WR;
  const char* CTXT = wsb + B_CTXT;
  const float* wsf = (const float*)wsb;
  const int bbase0 = lo16 * 1024 + g * 16;
  const int bswz = (lo16 & 7) << 4;
  const int swzq = (lo16 & 7) << 4;

  // ---- stage x,y (non-temporal); init ACC = 0.25*(x+y) ----
  {
    int prow = t >> 6, j = t & 63;
    const f32x4* gx = (const f32x4*)(x + (size_t)(n0 + prow) * 512 + j * 8);
    const f32x4* gy = (const f32x4*)(y + (size_t)(n0 + prow) * 512 + j * 8);
    f32x4 x0 = __builtin_nontemporal_load(gx);
    f32x4 x1 = __builtin_nontemporal_load(gx + 1);
    f32x4 y0 = __builtin_nontemporal_load(gy);
    f32x4 y1 = __builtin_nontemporal_load(gy + 1);
    int byte = (prow * 1024 + j * 16) ^ ((prow & 7) << 4);
    uint4 pk;
    pk.x = pack2(x0[0], x0[1]); pk.y = pack2(x0[2], x0[3]);
    pk.z = pack2(x1[0], x1[1]); pk.w = pack2(x1[2], x1[3]);
    *(uint4*)(Xl + byte) = pk;
    pk.x = pack2(y0[0], y0[1]); pk.y = pack2(y0[2], y0[3]);
    pk.z = pack2(y1[0], y1[1]); pk.w = pack2(y1[2], y1[3]);
    *(uint4*)(Yl + byte) = pk;
    int abase = prow * 2048 + j * 32;
    int aswz = (prow & 7) << 4;
    f32x4 a0 = 0.25f * (x0 + y0);
    f32x4 a1 = 0.25f * (x1 + y1);
    *(f32x4*)(ACCb + (abase ^ aswz)) = a0;
    *(f32x4*)(ACCb + ((abase + 16) ^ aswz)) = a1;
  }
  __syncthreads();

  // ---- main GEMM: wave tw owns Wbig tile pair (2tw, 2tw+1); 4 MFMAs per ks ----
  f32x4 axT0 = {0,0,0,0}, ayT0 = {0,0,0,0}, axT1 = {0,0,0,0}, ayT1 = {0,0,0,0};
  {
    int t0 = tw * 2;
    const char* ap = Wbig + t0 * 16384 + l * 16;
    __builtin_amdgcn_s_setprio(1);
#pragma unroll
    for (int ks = 0; ks < 16; ++ks) {
      bf16x8 bx0 = *(const bf16x8*)(Xl + ((bbase0 + ks * 64) ^ bswz));
      bf16x8 by0 = *(const bf16x8*)(Yl + ((bbase0 + ks * 64) ^ bswz));
      bf16x8 af0 = *(const bf16x8*)(ap + ks * 1024);
      bf16x8 af1 = *(const bf16x8*)(ap + 16384 + ks * 1024);
      axT0 = MFMA(af0, bx0, axT0); ayT0 = MFMA(af0, by0, ayT0);
      axT1 = MFMA(af1, bx0, axT1); ayT1 = MFMA(af1, by0, ayT1);
    }
    __builtin_amdgcn_s_setprio(0);
  }

  unsigned Qy[4];  // b=1 packed Q

  if (tw < 8) {  // Q head tw: 2 softmaxes (b0 -> Ql, b1 -> regs)
    int hh = tw;
    unsigned o[4];
    softmax_pack(axT0, axT1, bq, hh, g, o);
    {
      int base_q = lo16 * 512 + hh * 64 + g * 8;
      uint2 w0; w0.x = o[0]; w0.y = o[1];
      uint2 w1; w1.x = o[2]; w1.y = o[3];
      *(uint2*)(Ql + (base_q ^ swzq)) = w0;
      *(uint2*)(Ql + ((base_q + 32) ^ swzq)) = w1;
    }
    softmax_pack(ayT0, ayT1, bq, hh, g, Qy);
  } else {  // L tile pair: accumulate 0.25*(Lx+Ly) into ACC
    int tile0 = tw * 2 - 16;
    int row = lo16, rsw = (row & 7) << 4;
#pragma unroll
    for (int half = 0; half < 2; ++half) {
      f32x4 axs = half ? axT1 : axT0;
      f32x4 ays = half ? ayT1 : ayT0;
      int ch4 = 64 + (tile0 + half) * 4 + g;
      int ab = (row * 2048 + ch4 * 16) ^ rsw;
      f32x4 cur = *(const f32x4*)(ACCb + ab);
      cur += 0.25f * (axs + ays);
      *(f32x4*)(ACCb + ab) = cur;
    }
  }

  // ---- delta (wave 15): both b, one weight read ----
  if (tw == 15) {
    f32x4 adx = {0,0,0,0}, ady = {0,0,0,0};
    const char* ap = Wbig + 32 * 16384 + l * 16;
#pragma unroll
    for (int ks = 0; ks < 16; ++ks) {
      bf16x8 bx0 = *(const bf16x8*)(Xl + ((bbase0 + ks * 64) ^ bswz));
      bf16x8 by0 = *(const bf16x8*)(Yl + ((bbase0 + ks * 64) ^ bswz));
      bf16x8 af = *(const bf16x8*)(ap + ks * 1024);
      adx = MFMA(af, bx0, adx); ady = MFMA(af, by0, ady);
    }
    if (g == 0) {
      int pos = n0 + lo16;
      float base_gx = -1.f + 2.f * (float)pos / 32767.f;
#pragma unroll
      for (int b = 0; b < 2; ++b) {
        f32x4 ad = b ? ady : adx;
        float d0 = ad[0] + wsf[(B_CONSTD / 4) + b * 2 + 0];
        float d1 = ad[1] + wsf[(B_CONSTD / 4) + b * 2 + 1];
        float gxv = base_gx + d0;
        float gyv = -1.f + d1;
        float ix = gxv * 0.5f, iy = gyv * 0.5f;
        float wx = fminf(fmaxf(1.f - fabsf(ix), 0.f), 1.f);
        float wy = fminf(fmaxf(1.f - fabsf(iy), 0.f), 1.f);
        wgtl[b * 16 + lo16] = wx * wy;
      }
    }
  }

  // ---- att (Q waves): b0 via Ql, swap in Qy, b1, pack attS ----
  if (tw < 8) {
    int hh = tw;
    f32x4 at0 = {0,0,0,0}, at1 = {0,0,0,0};
    {
      bf16x8 qf = *(const bf16x8*)(Ql + ((lo16 * 512 + hh * 64 + g * 16) ^ swzq));
      const char* cp = CTXT + (0 * 8 + hh) * 2048 + l * 16;
      bf16x8 c0 = *(const bf16x8*)(cp);
      bf16x8 c1 = *(const bf16x8*)(cp + 1024);
      at0 = MFMA(c0, qf, at0);
      at1 = MFMA(c1, qf, at1);
    }
    {
      int base_q = lo16 * 512 + hh * 64 + g * 8;
      uint2 w0; w0.x = Qy[0]; w0.y = Qy[1];
      uint2 w1; w1.x = Qy[2]; w1.y = Qy[3];
      *(uint2*)(Ql + (base_q ^ swzq)) = w0;
      *(uint2*)(Ql + ((base_q + 32) ^ swzq)) = w1;
    }
    {
      bf16x8 qf = *(const bf16x8*)(Ql + ((lo16 * 512 + hh * 64 + g * 16) ^ swzq));
      const char* cp = CTXT + (1 * 8 + hh) * 2048 + l * 16;
      bf16x8 c0 = *(const bf16x8*)(cp);
      bf16x8 c1 = *(const bf16x8*)(cp + 1024);
      at0 = MFMA(c0, qf, at0);
      at1 = MFMA(c1, qf, at1);
    }
#pragma unroll
    for (int m = 0; m < 2; ++m) {
      f32x4 v = m ? at1 : at0;
      uint2 wv;
      wv.x = pack2(v[0], v[1]); wv.y = pack2(v[2], v[3]);
      int byte = (lo16 * 512 + hh * 64 + m * 32 + g * 8) ^ swzq;
      *(uint2*)(Ql + byte) = wv;
    }
  }
  __syncthreads();  // attS + wgtl + ACC(L) complete

  // ---- reprojection: wave tw owns WR tile pair (2tw, 2tw+1) ----
  {
    int T0 = tw * 2;
    f32x4 r0 = {0,0,0,0}, r1 = {0,0,0,0};
    const char* ap = WRp + T0 * 8192 + l * 16;
    __builtin_amdgcn_s_setprio(1);
#pragma unroll
    for (int ks = 0; ks < 8; ++ks) {
      bf16x8 br0 = *(const bf16x8*)(Ql + ((lo16 * 512 + g * 16 + ks * 64) ^ swzq));
      bf16x8 a0 = *(const bf16x8*)(ap + ks * 1024);
      bf16x8 a1 = *(const bf16x8*)(ap + 8192 + ks * 1024);
      r0 = MFMA(a0, br0, r0); r1 = MFMA(a1, br0, r1);
    }
    __builtin_amdgcn_s_setprio(0);
    int row = lo16, rsw = (row & 7) << 4;
#pragma unroll
    for (int half = 0; half < 2; ++half) {
      f32x4 rr = half ? r1 : r0;
      int ch4 = (T0 + half) * 4 + g;
      int ab = (row * 2048 + ch4 * 16) ^ rsw;
      f32x4 cur = *(const f32x4*)(ACCb + ab);
      cur += 0.25f * rr;
      *(f32x4*)(ACCb + ab) = cur;
    }
  }
  __syncthreads();  // ACC final

  // ---- output pass: ACC + bias + CAM-sampled term (NT store) ----
  const float* bo = wsf + (B_BIASO / 4);
#pragma unroll
  for (int i = 0; i < 2; ++i) {
    int idx = i * 1024 + t;      // f32x4 index over [16][128]
    int pos = idx >> 7, c4 = idx & 127;
    int ab = (pos * 2048 + c4 * 16) ^ ((pos & 7) << 4);
    f32x4 acc = *(const f32x4*)(ACCb + ab);
    f32x4 bb = *(const f32x4*)(bo + c4 * 4);
    if (c4 < 64) {
      f32x4 h20 = *(const f32x4*)(wsf + (B_HIGH2 / 4) + c4 * 4);
      f32x4 h21 = *(const f32x4*)(wsf + (B_HIGH2 / 4) + 256 + c4 * 4);
      float wg0 = wgtl[pos], wg1 = wgtl[16 + pos];
      acc += (0.25f * wg0) * h20 + (0.25f * wg1) * h21;
    }
    acc += bb;
    __builtin_nontemporal_store(acc, (f32x4*)(out + (size_t)(n0 + pos) * 512 + c4 * 4));
  }
}

extern "C" void kernel_launch(void* const* d_in, const int* in_sizes, int n_in,
                              void* d_out, int out_size, void* d_ws, size_t ws_size,
                              hipStream_t stream) {
  const float* x = (const float*)d_in[0];
  const float* y = (const float*)d_in[1];
  const float* ea_wk = (const float*)d_in[2];
  const float* ea_bk = (const float*)d_in[3];
  const float* ea_wq = (const float*)d_in[4];
  const float* ea_bq = (const float*)d_in[5];
  const float* ea_wv = (const float*)d_in[6];
  const float* ea_bv = (const float*)d_in[7];
  const float* ea_wr = (const float*)d_in[8];
  const float* ea_br = (const float*)d_in[9];
  const float* pool_w1 = (const float*)d_in[10];
  const float* pool_bn1 = (const float*)d_in[11];
  const float* pool_w2 = (const float*)d_in[12];
  const float* pool_bn2 = (const float*)d_in[13];
  const float* adapt_w1 = (const float*)d_in[14];
  const float* adapt_bn1 = (const float*)d_in[15];
  const float* adapt_w2 = (const float*)d_in[16];
  const float* adapt_bn2 = (const float*)d_in[17];
  const float* delta_w1 = (const float*)d_in[18];
  const float* delta_bn1 = (const float*)d_in[19];
  const float* delta_w2 = (const float*)d_in[20];
  char* ws = (char*)d_ws;
  float* out = (float*)d_out;

  kFuse1<<<2176, 512, 0, stream>>>(adapt_w1, adapt_bn1, adapt_w2, adapt_bn2,
                                   ea_wq, ea_wk, ea_wv, ea_wr, pool_w1, pool_w2,
                                   delta_w1, ws);
  kW2<<<8, 512, 0, stream>>>(delta_w1, delta_bn1, delta_w2, ws);
  kPackB<<<272, 512, 0, stream>>>(ws);
  k1_reduce<<<1024, 1024, 0, stream>>>(x, y, ea_bk, ea_bv, ws, out);
  k1b<<<224, 512, 0, stream>>>(out, ws);
  k2_finalize<<<33, 512, 0, stream>>>(pool_bn1, pool_bn2, delta_bn1, delta_w2, ea_br, ws);
  k3_main<<<2048, 1024, 0, stream>>>(x, y, ea_bq, ws, out);
}

// Round 24
// 297.186 us; speedup vs baseline: 1.0881x; 1.0881x over previous
//
#include <hip/hip_runtime.h>
#include <math.h>

// ---------------- ws byte offsets ----------------
#define B_CTXC   0          // single summed ctx [2][8][32][32] f32 = 65536 B
#define B_ZP     524288     // [2][256] f32
#define B_COLS   526336     // [2][512] f32
#define B_HIGH2  530432     // [2][256] f32
#define B_CONSTD 532480     // [2][2] f32 (+pad)
#define B_BIASO  532544     // [512] f32
#define B_CPP    534592     // [256] f32 (c'')
#define B_CTXT   535616     // [2][8] x 2 tiles x 1KB bf16, fragment-linear
#define B_WDD    568384     // [2][256] f32
#define B_WDX    570432     // [2][512] f32
#define B_WL     574528     // [256][512] f32 (W_L'')
#define B_WBIG   1098816    // 33 tiles x 16KB bf16, fragment-linear
#define B_WKV    1639488    // 32 tiles x 16KB bf16, fragment-linear
#define B_WR     2163776    // 32 tiles x 8KB bf16, fragment-linear
#define B_PW1T   2425920    // [512][512] f32 transposed
#define B_PW2T   3474496    // [512][256] f32 transposed
#define B_D1BT   3998784    // [256][256] f32 transposed
// d_out scratch (before k3 overwrites): [1024][8192] u32 ctx partials at u32
// index 0 (32MB), [1024][1536] f32 red partials at float offset 8388608.

typedef __attribute__((ext_vector_type(8))) short bf16x8;
typedef __attribute__((ext_vector_type(4))) float f32x4;

#define MFMA(a, b, c) __builtin_amdgcn_mfma_f32_16x16x32_bf16(a, b, c, 0, 0, 0)
#define EVSWZ(row) ((((row) >> 1) & 3) << 4)

__device__ inline unsigned f2bfu(float f) {
  unsigned u = __float_as_uint(f);
  return (u + 0x7FFFu + ((u >> 16) & 1u)) >> 16;
}
__device__ inline unsigned pack2(float a, float b) { return f2bfu(a) | (f2bfu(b) << 16); }

// softmax over 32 head-channels -> 4 packed bf16x2 words
__device__ inline void softmax_pack(f32x4 a0, f32x4 a1, const float* __restrict__ bq,
                                    int hh, int g, unsigned o[4]) {
  float q[8], e[8];
  float mx = -1e30f;
#pragma unroll
  for (int r = 0; r < 4; ++r) {
    q[r] = a0[r] + bq[hh * 32 + g * 4 + r];
    q[4 + r] = a1[r] + bq[hh * 32 + 16 + g * 4 + r];
    mx = fmaxf(mx, fmaxf(q[r], q[4 + r]));
  }
  mx = fmaxf(mx, __shfl_xor(mx, 16, 64));
  mx = fmaxf(mx, __shfl_xor(mx, 32, 64));
  float sm = 0.f;
#pragma unroll
  for (int r = 0; r < 8; ++r) { e[r] = __expf(q[r] - mx); sm += e[r]; }
  sm += __shfl_xor(sm, 16, 64);
  sm += __shfl_xor(sm, 32, 64);
  float inv = 1.f / sm;
  o[0] = pack2(e[0] * inv, e[1] * inv); o[1] = pack2(e[2] * inv, e[3] * inv);
  o[2] = pack2(e[4] * inv, e[5] * inv); o[3] = pack2(e[6] * inv, e[7] * inv);
}

// ---------------- kFuse1: blocks 0-255 = kW1; blocks 256+ = independent packs ----------------
__global__ __launch_bounds__(512) void kFuse1(
    const float* __restrict__ a1, const float* __restrict__ abn1,
    const float* __restrict__ a2, const float* __restrict__ abn2,
    const float* __restrict__ wq, const float* __restrict__ wk, const float* __restrict__ wv,
    const float* __restrict__ wr, const float* __restrict__ pw1, const float* __restrict__ pw2,
    const float* __restrict__ d1, char* __restrict__ wsb) {
  __shared__ float S1[512], F1[512], redu[512];
  const int t = threadIdx.x;
  float* wsf = (float*)wsb;
  unsigned short* u16 = (unsigned short*)wsb;
  if (blockIdx.x < 256) {
    const int o = blockIdx.x;
    {
      float gg = abn1[t], be = abn1[512 + t], mn = abn1[1024 + t], va = abn1[1536 + t];
      float s = gg * rsqrtf(va + 1e-5f);
      S1[t] = s; F1[t] = be - mn * s;
    }
    float g2 = abn2[o], be2 = abn2[256 + o], mn2 = abn2[512 + o], va2 = abn2[768 + o];
    float s2 = g2 * rsqrtf(va2 + 1e-5f);
    float f2v = be2 - mn2 * s2;
    __syncthreads();
    float acc = 0.f;
    const float* a2r = a2 + o * 512;
    for (int m = 0; m < 512; ++m) acc = fmaf(a2r[m] * S1[m], a1[m * 512 + t], acc);
    wsf[(B_WL / 4) + o * 512 + t] = s2 * acc;
    redu[t] = a2r[t] * F1[t];
    __syncthreads();
    for (int sft = 256; sft >= 1; sft >>= 1) {
      if (t < sft) redu[t] += redu[t + sft];
      __syncthreads();
    }
    if (t == 0) wsf[(B_CPP / 4) + o] = s2 * redu[0] + f2v;
    return;
  }
  int i = (blockIdx.x - 256) * 512 + t;
  if (i < 131072) {  // Wbig tiles 0-15 (wq rows)
    int T = i >> 13, r = i & 8191;
    int ks = r >> 9, l = (r >> 3) & 63, j = r & 7;
    int row = T * 16 + (l & 15);
    int col = ks * 32 + (l >> 4) * 8 + j;
    u16[(B_WBIG / 2) + i] = (unsigned short)f2bfu(wq[row * 512 + col]);
    return;
  }
  i -= 131072;
  if (i < 262144) {  // Wkv: 32 tiles, K=512
    int T = i >> 13, r = i & 8191;
    int ks = r >> 9, l = (r >> 3) & 63, j = r & 7;
    int row = T * 16 + (l & 15);
    int col = ks * 32 + (l >> 4) * 8 + j;
    float v = row < 256 ? wk[row * 512 + col] : wv[(row - 256) * 512 + col];
    u16[(B_WKV / 2) + i] = (unsigned short)f2bfu(v);
    return;
  }
  i -= 262144;
  if (i < 131072) {  // WR: 32 tiles, K=256
    int T = i >> 12, r = i & 4095;
    int ks = r >> 9, l = (r >> 3) & 63, j = r & 7;
    int row = T * 16 + (l & 15);
    int col = ks * 32 + (l >> 4) * 8 + j;
    u16[(B_WR / 2) + i] = (unsigned short)f2bfu(wr[row * 256 + col]);
    return;
  }
  i -= 131072;
  if (i < 262144) { int o = i >> 9, c = i & 511; wsf[(B_PW1T / 4) + c * 512 + o] = pw1[i]; return; }
  i -= 262144;
  if (i < 131072) { int o = i >> 9, c = i & 511; wsf[(B_PW2T / 4) + c * 256 + o] = pw2[i]; return; }
  i -= 131072;
  if (i < 65536) { int o = i >> 8, v = i & 255; wsf[(B_D1BT / 4) + v * 256 + o] = d1[o * 512 + 256 + v]; }
}

// ---------------- kW2: W_dd, W_dx — 8 blocks x 64 columns ----------------
__global__ __launch_bounds__(512) void kW2(
    const float* __restrict__ d1, const float* __restrict__ dbn1,
    const float* __restrict__ d2, char* __restrict__ wsb) {
  __shared__ float SD[256], WDDl[512], part[512];
  const int t = threadIdx.x, blk = blockIdx.x;
  float* wsf = (float*)wsb;
  if (t < 256) {
    float gg = dbn1[t], va = dbn1[768 + t];
    SD[t] = gg * rsqrtf(va + 1e-5f);
  }
  __syncthreads();
  {
    int j = t >> 8, v = t & 255;
    float acc = 0.f;
    for (int o = 0; o < 256; ++o) acc = fmaf(d2[j * 256 + o] * SD[o], d1[o * 512 + v], acc);
    WDDl[t] = acc;
    if (blk == 0) wsf[(B_WDD / 4) + t] = acc;
  }
  __syncthreads();
  const int cl = t & 63, vp = t >> 6;
  const int c = blk * 64 + cl;
  float acc0 = 0.f, acc1 = 0.f;
  for (int v = vp * 32; v < vp * 32 + 32; ++v) {
    float wl = wsf[(B_WL / 4) + v * 512 + c];
    acc0 = fmaf(WDDl[v], wl, acc0);
    acc1 = fmaf(WDDl[256 + v], wl, acc1);
  }
  part[t] = acc0;
  __syncthreads();
  if (t < 64) {
    float s = 0.f;
#pragma unroll
    for (int p2 = 0; p2 < 8; ++p2) s += part[p2 * 64 + t];
    wsf[(B_WDX / 4) + blk * 64 + t] = s;
  }
  __syncthreads();
  part[t] = acc1;
  __syncthreads();
  if (t < 64) {
    float s = 0.f;
#pragma unroll
    for (int p2 = 0; p2 < 8; ++p2) s += part[p2 * 64 + t];
    wsf[(B_WDX / 4) + 512 + blk * 64 + t] = s;
  }
}

// ---------------- kPackB: Wbig tiles 16-32 (depend on W_L / WDX) ----------------
__global__ __launch_bounds__(512) void kPackB(char* __restrict__ wsb) {
  float* wsf = (float*)wsb;
  unsigned short* u16 = (unsigned short*)wsb;
  int i = blockIdx.x * 512 + threadIdx.x + 131072;  // Wbig element index, tiles 16..32
  if (i >= 270336) return;
  int T = i >> 13, r = i & 8191;
  int ks = r >> 9, l = (r >> 3) & 63, j = r & 7;
  int row = T * 16 + (l & 15);
  int col = ks * 32 + (l >> 4) * 8 + j;
  float v;
  if (row < 512) v = wsf[(B_WL / 4) + (row - 256) * 512 + col];
  else if (row < 514) v = wsf[(B_WDX / 4) + (row - 512) * 512 + col];
  else v = 0.f;
  u16[(B_WBIG / 2) + i] = (unsigned short)f2bfu(v);
}

// ---------------- k1: LDS-overlaid, NT-streaming x/y ----------------
__global__ __launch_bounds__(1024, 2) void k1_reduce(
    const float* __restrict__ x, const float* __restrict__ y,
    const float* __restrict__ bk, const float* __restrict__ bv,
    const char* __restrict__ wsb, float* __restrict__ outp) {
  __shared__ __align__(16) unsigned char XYl[65536];  // Xl|Yl -> PS -> el/vl
  __shared__ float Red[1536];
  unsigned char* Xl = XYl;
  unsigned char* Yl = XYl + 32768;
  float* PSf = (float*)XYl;
  unsigned char* elx = XYl;
  unsigned char* ely = XYl + 16384;
  unsigned char* vlx = XYl + 32768;
  unsigned char* vly = XYl + 49152;
  const int t = threadIdx.x;
  const int tw = t >> 6, lo16 = t & 15, g = (t >> 4) & 3, l = t & 63;
  const char* Wkv = wsb + B_WKV;

  if (t < 512) Red[t] = 0.f;
  float csum[2][8];
#pragma unroll
  for (int b2 = 0; b2 < 2; ++b2)
#pragma unroll
    for (int i = 0; i < 8; ++i) csum[b2][i] = 0.f;
  const int n0 = blockIdx.x * 32;
  const int bbase0 = lo16 * 1024 + g * 16;
  const int bbase1 = bbase0 + 16384;
  const int bswz = (lo16 & 7) << 4;
  const int pp0 = lo16, pp1 = 16 + lo16;

#pragma unroll
  for (int r = 0; r < 2; ++r) {
    int chunk = r * 1024 + t;
    int prow = chunk >> 6, j = chunk & 63;
    const f32x4* gx = (const f32x4*)(x + (size_t)(n0 + prow) * 512 + j * 8);
    const f32x4* gy = (const f32x4*)(y + (size_t)(n0 + prow) * 512 + j * 8);
    f32x4 x0 = __builtin_nontemporal_load(gx);
    f32x4 x1 = __builtin_nontemporal_load(gx + 1);
    f32x4 y0 = __builtin_nontemporal_load(gy);
    f32x4 y1 = __builtin_nontemporal_load(gy + 1);
#pragma unroll
    for (int q2 = 0; q2 < 4; ++q2) {
      csum[0][q2] += x0[q2]; csum[0][4 + q2] += x1[q2];
      csum[1][q2] += y0[q2]; csum[1][4 + q2] += y1[q2];
    }
    int byte = (prow * 1024 + j * 16) ^ ((prow & 7) << 4);
    uint4 pk;
    pk.x = pack2(x0[0], x0[1]); pk.y = pack2(x0[2], x0[3]);
    pk.z = pack2(x1[0], x1[1]); pk.w = pack2(x1[2], x1[3]);
    *(uint4*)(Xl + byte) = pk;
    pk.x = pack2(y0[0], y0[1]); pk.y = pack2(y0[2], y0[3]);
    pk.z = pack2(y1[0], y1[1]); pk.w = pack2(y1[2], y1[3]);
    *(uint4*)(Yl + byte) = pk;
  }
  __syncthreads();  // (A)

  f32x4 ax0p0 = {0,0,0,0}, ax0p1 = {0,0,0,0}, ay0p0 = {0,0,0,0}, ay0p1 = {0,0,0,0};
  f32x4 ax1p0 = {0,0,0,0}, ax1p1 = {0,0,0,0}, ay1p0 = {0,0,0,0}, ay1p1 = {0,0,0,0};
  {
    int t0 = tw * 2;
    const char* ap = Wkv + t0 * 16384 + l * 16;
    __builtin_amdgcn_s_setprio(1);
#pragma unroll
    for (int ks = 0; ks < 16; ++ks) {
      bf16x8 bx0 = *(const bf16x8*)(Xl + ((bbase0 + ks * 64) ^ bswz));
      bf16x8 bx1 = *(const bf16x8*)(Xl + ((bbase1 + ks * 64) ^ bswz));
      bf16x8 by0 = *(const bf16x8*)(Yl + ((bbase0 + ks * 64) ^ bswz));
      bf16x8 by1 = *(const bf16x8*)(Yl + ((bbase1 + ks * 64) ^ bswz));
      bf16x8 af0 = *(const bf16x8*)(ap + ks * 1024);
      bf16x8 af1 = *(const bf16x8*)(ap + 16384 + ks * 1024);
      ax0p0 = MFMA(af0, bx0, ax0p0); ax0p1 = MFMA(af0, bx1, ax0p1);
      ay0p0 = MFMA(af0, by0, ay0p0); ay0p1 = MFMA(af0, by1, ay0p1);
      ax1p0 = MFMA(af1, bx0, ax1p0); ax1p1 = MFMA(af1, bx1, ax1p1);
      ay1p0 = MFMA(af1, by0, ay1p0); ay1p1 = MFMA(af1, by1, ay1p1);
    }
    __builtin_amdgcn_s_setprio(0);
  }
  float ex0[2][4], ex1[2][4], ey0[2][4], ey1[2][4];
  if (tw < 8) {
    int t0 = tw * 2, t1 = t0 + 1;
#pragma unroll
    for (int pt2 = 0; pt2 < 2; ++pt2) {
      f32x4 Ax0 = pt2 ? ax0p1 : ax0p0, Ax1 = pt2 ? ax1p1 : ax1p0;
      f32x4 Ay0 = pt2 ? ay0p1 : ay0p0, Ay1 = pt2 ? ay1p1 : ay1p0;
#pragma unroll
      for (int r = 0; r < 4; ++r) {
        float bk0 = bk[t0 * 16 + g * 4 + r], bk1 = bk[t1 * 16 + g * 4 + r];
        ex0[pt2][r] = __expf(Ax0[r] + bk0); ey0[pt2][r] = __expf(Ay0[r] + bk0);
        ex1[pt2][r] = __expf(Ax1[r] + bk1); ey1[pt2][r] = __expf(Ay1[r] + bk1);
      }
#pragma unroll
      for (int r = 0; r < 4; ++r) {
        float v0 = ex0[pt2][r], v1 = ex1[pt2][r], v2 = ey0[pt2][r], v3 = ey1[pt2][r];
        for (int m = 8; m >= 1; m >>= 1) {
          v0 += __shfl_xor(v0, m, 16); v1 += __shfl_xor(v1, m, 16);
          v2 += __shfl_xor(v2, m, 16); v3 += __shfl_xor(v3, m, 16);
        }
        if (lo16 == 0) {
          atomicAdd(&Red[t0 * 16 + g * 4 + r], v0);
          atomicAdd(&Red[t1 * 16 + g * 4 + r], v1);
          atomicAdd(&Red[256 + t0 * 16 + g * 4 + r], v2);
          atomicAdd(&Red[256 + t1 * 16 + g * 4 + r], v3);
        }
      }
    }
  }
  __syncthreads();  // (B)

#pragma unroll
  for (int b = 0; b < 2; ++b)
#pragma unroll
    for (int i = 0; i < 8; ++i) PSf[t * 16 + b * 8 + i] = csum[b][i];
  __syncthreads();  // (C)
  {
    int s = t, b = s >> 9, ch = s & 511, tlow = ch >> 3, ii = ch & 7;
    float sum = 0.f;
#pragma unroll
    for (int w2 = 0; w2 < 16; ++w2) sum += PSf[(w2 * 64 + tlow) * 16 + b * 8 + ii];
    Red[512 + s] = sum;
  }
  __syncthreads();  // (D)

  if (tw < 8) {
    int t0 = tw * 2, t1 = t0 + 1;
#pragma unroll
    for (int pt2 = 0; pt2 < 2; ++pt2) {
      int pp = pt2 ? pp1 : pp0;
#pragma unroll
      for (int r = 0; r < 4; ++r) {
        int row0 = t0 * 16 + g * 4 + r;
        int row1 = t1 * 16 + g * 4 + r;
        int a0 = (row0 * 64 + pp * 2) ^ EVSWZ(row0);
        int a1 = (row1 * 64 + pp * 2) ^ EVSWZ(row1);
        *(unsigned short*)(elx + a0) = (unsigned short)f2bfu(ex0[pt2][r]);
        *(unsigned short*)(elx + a1) = (unsigned short)f2bfu(ex1[pt2][r]);
        *(unsigned short*)(ely + a0) = (unsigned short)f2bfu(ey0[pt2][r]);
        *(unsigned short*)(ely + a1) = (unsigned short)f2bfu(ey1[pt2][r]);
      }
    }
  } else {
    int t0 = tw * 2, t1 = t0 + 1;
#pragma unroll
    for (int pt2 = 0; pt2 < 2; ++pt2) {
      f32x4 Ax0 = pt2 ? ax0p1 : ax0p0, Ax1 = pt2 ? ax1p1 : ax1p0;
      f32x4 Ay0 = pt2 ? ay0p1 : ay0p0, Ay1 = pt2 ? ay1p1 : ay1p0;
      int pp = pt2 ? pp1 : pp0;
#pragma unroll
      for (int r = 0; r < 4; ++r) {
        int row0 = (t0 - 16) * 16 + g * 4 + r;
        int row1 = (t1 - 16) * 16 + g * 4 + r;
        float bv0 = bv[row0], bv1 = bv[row1];
        int a0 = (row0 * 64 + pp * 2) ^ EVSWZ(row0);
        int a1 = (row1 * 64 + pp * 2) ^ EVSWZ(row1);
        *(unsigned short*)(vlx + a0) = (unsigned short)f2bfu(Ax0[r] + bv0);
        *(unsigned short*)(vlx + a1) = (unsigned short)f2bfu(Ax1[r] + bv1);
        *(unsigned short*)(vly + a0) = (unsigned short)f2bfu(Ay0[r] + bv0);
        *(unsigned short*)(vly + a1) = (unsigned short)f2bfu(Ay1[r] + bv1);
      }
    }
  }
  __syncthreads();  // (E)

  {
    const int h2 = tw & 7, bsel = tw >> 3;
    const unsigned char* el = bsel ? ely : elx;
    const unsigned char* vl = bsel ? vly : vlx;
    unsigned* ctxp = (unsigned*)outp + (size_t)blockIdx.x * 8192;
#pragma unroll
    for (int m = 0; m < 2; ++m) {
      int rowe = h2 * 32 + m * 16 + lo16;
      bf16x8 ea = *(const bf16x8*)(el + ((rowe * 64 + g * 16) ^ EVSWZ(rowe)));
      f32x4 c0 = {0.f, 0.f, 0.f, 0.f}, c1 = {0.f, 0.f, 0.f, 0.f};
      {
        int rowv = h2 * 32 + lo16;
        bf16x8 vb = *(const bf16x8*)(vl + ((rowv * 64 + g * 16) ^ EVSWZ(rowv)));
        c0 = MFMA(ea, vb, c0);
      }
      {
        int rowv = h2 * 32 + 16 + lo16;
        bf16x8 vb = *(const bf16x8*)(vl + ((rowv * 64 + g * 16) ^ EVSWZ(rowv)));
        c1 = MFMA(ea, vb, c1);
      }
#pragma unroll
      for (int r = 0; r < 4; ++r)
        __builtin_nontemporal_store(pack2(c0[r], c1[r]),
            &ctxp[((bsel * 2 + m) * 4 + r) * 512 + h2 * 64 + l]);
    }
    float* redp = outp + 8388608 + blockIdx.x * 1536;
    for (int i = t; i < 1536; i += 1024) __builtin_nontemporal_store(Red[i], &redp[i]);
  }
}

// ---------------- k1b: tree-reduce (128 ctx + 96 red blocks) ----------------
__global__ __launch_bounds__(512) void k1b(const float* __restrict__ outp, char* __restrict__ wsb) {
  __shared__ float R[512];
  const int t = threadIdx.x, blk = blockIdx.x;
  float* wsf = (float*)wsb;
  if (blk < 128) {  // ctx: 64 slots per block, 8 partial-sum lanes each
    int sl = t & 63, part = t >> 6;  // part 0..7
    int slot = blk * 64 + sl;
    const unsigned* p = (const unsigned*)outp;
    float s0 = 0.f, s1 = 0.f;
    for (int c = part * 128; c < part * 128 + 128; ++c) {
      unsigned wv = __builtin_nontemporal_load(&p[(size_t)c * 8192 + slot]);
      s0 += __uint_as_float(wv << 16);
      s1 += __uint_as_float(wv & 0xffff0000u);
    }
    R[sl * 8 + part] = s0;
    __syncthreads();
    float sum0 = 0.f;
#pragma unroll
    for (int p2 = 0; p2 < 8; ++p2) sum0 += R[sl * 8 + p2];
    __syncthreads();
    R[sl * 8 + part] = s1;
    __syncthreads();
    float sum1 = 0.f;
#pragma unroll
    for (int p2 = 0; p2 < 8; ++p2) sum1 += R[sl * 8 + p2];
    if (part == 0) {
      int t_ = slot & 511, bmr = slot >> 9;
      int r = bmr & 3, m = (bmr >> 2) & 1, b = bmr >> 3;
      int h = t_ >> 6, g = (t_ >> 4) & 3, lo16 = t_ & 15;
      int klocal = m * 16 + g * 4 + r;
      int base = ((b * 8 + h) * 32 + klocal) * 32;
      wsf[(B_CTXC / 4) + base + lo16] = sum0;
      wsf[(B_CTXC / 4) + base + 16 + lo16] = sum1;
    }
  } else {  // red: 96 blocks x 16 slots, 32-way copy split
    int sj = t & 15, part = t >> 4;
    int slot = (blk - 128) * 16 + sj;
    const float* rp = outp + 8388608;
    float s = 0.f;
    for (int cc = part * 32; cc < part * 32 + 32; ++cc)
      s += __builtin_nontemporal_load(&rp[(size_t)cc * 1536 + slot]);
    R[t] = s;
    __syncthreads();
    if (t < 16) {
      float sum = 0.f;
#pragma unroll
      for (int p2 = 0; p2 < 32; ++p2) sum += R[t + p2 * 16];
      int j = (blk - 128) * 16 + t;
      if (j < 512) wsf[(B_ZP / 4) + j] = sum;
      else wsf[(B_COLS / 4) + (j - 512)] = sum;
    }
  }
}

// ---------------- k2: blocks 0-15 ctx normalize (1024 thr); block 16 pool chain ----------------
__global__ __launch_bounds__(1024) void k2_finalize(
    const float* __restrict__ pbn1, const float* __restrict__ pbn2,
    const float* __restrict__ dbn1, const float* __restrict__ d2,
    const float* __restrict__ ea_br, char* __restrict__ wsb) {
  __shared__ float HI[1024], H1[1024], H2l[512], VB[512], slot[4];
  const int t = threadIdx.x;
  float* wsf = (float*)wsb;
  unsigned short* u16 = (unsigned short*)wsb;
  if (blockIdx.x < 16) {
    int idx = blockIdx.x * 1024 + t;
    float s = wsf[(B_CTXC / 4) + idx];
    int v = idx & 31, row = idx >> 5;
    int b = row >> 8, kr = row & 255;
    int hh = kr >> 5, kh = kr & 31;
    float val = s / wsf[(B_ZP / 4) + b * 256 + kr];
    int m = v >> 4;
    int lane = (v & 15) + ((kh >> 3) << 4);
    int j = kh & 7;
    u16[(B_CTXT / 2) + (((b * 8 + hh) * 2 + m) << 9) + lane * 8 + j] = (unsigned short)f2bfu(val);
    return;
  }
  // pool chain on 1024 threads
  if (t < 4) slot[t] = 0.f;
  HI[t] = wsf[(B_COLS / 4) + t] * (1.f / 32768.f);
  __syncthreads();
  {
    int o = t & 511, b = t >> 9;  // 1024 threads: perfect (o, b) split
    float gg = pbn1[o], be = pbn1[512 + o], mn = pbn1[1024 + o], va = pbn1[1536 + o];
    float sc = gg * rsqrtf(va + 1e-5f), sh = be - mn * sc;
    float acc = 0.f;
    for (int c = 0; c < 512; ++c) acc = fmaf(wsf[(B_PW1T / 4) + c * 512 + o], HI[b * 512 + c], acc);
    H1[b * 512 + o] = acc * sc + sh;
  }
  __syncthreads();
  if (t < 512) {
    int o = t & 255, b = t >> 8;  // 512 threads: (o, b) split
    float gg = pbn2[o], be = pbn2[256 + o], mn = pbn2[512 + o], va = pbn2[768 + o];
    float sc = gg * rsqrtf(va + 1e-5f), sh = be - mn * sc;
    float acc = 0.f;
    for (int c = 0; c < 512; ++c) acc = fmaf(wsf[(B_PW2T / 4) + c * 256 + o], H1[b * 512 + c], acc);
    float vv = acc * sc + sh;
    H2l[b * 256 + o] = vv;
    wsf[(B_HIGH2 / 4) + b * 256 + o] = vv;
  }
  __syncthreads();
  if (t < 512) {
    int o = t & 255, b = t >> 8;
    float gg = dbn1[o], be = dbn1[256 + o], mn = dbn1[512 + o], va = dbn1[768 + o];
    float sd = gg * rsqrtf(va + 1e-5f), fd = be - mn * sd;
    float acc = 0.f;
    for (int v = 0; v < 256; ++v) acc = fmaf(wsf[(B_D1BT / 4) + v * 256 + o], H2l[b * 256 + v], acc);
    VB[b * 256 + o] = sd * acc + fd;
  }
  __syncthreads();
  if (t < 256) {
    int o = t;
    for (int b = 0; b < 2; ++b)
      for (int j = 0; j < 2; ++j) atomicAdd(&slot[b * 2 + j], d2[j * 256 + o] * VB[b * 256 + o]);
    float cp = wsf[(B_CPP / 4) + o];
    for (int j = 0; j < 2; ++j) {
      float w = wsf[(B_WDD / 4) + j * 256 + o] * cp;
      atomicAdd(&slot[0 + j], w);
      atomicAdd(&slot[2 + j], w);
    }
  }
  __syncthreads();
  if (t < 4) wsf[(B_CONSTD / 4) + t] = slot[t];
  if (t < 512) {
    int o = t;
    float bb = 0.5f * ea_br[o];
    if (o >= 256) bb += 0.5f * wsf[(B_CPP / 4) + o - 256];
    wsf[(B_BIASO / 4) + o] = bb;
  }
}

// ---------------- k3: wave = weight tile-pair; NT-streaming x/y + output ----------------
__global__ __launch_bounds__(1024, 1) void k3_main(
    const float* __restrict__ x, const float* __restrict__ y,
    const float* __restrict__ bq, const char* __restrict__ wsb,
    float* __restrict__ out) {
  __shared__ __align__(16) unsigned char Xl[32768];
  __shared__ __align__(16) unsigned char Yl[32768];
  __shared__ __align__(16) unsigned char ACCb[65536];  // f32 [32 pos][512 ch], swizzled
  __shared__ __align__(16) unsigned char Ql[16384];    // 2 pt slabs x 8KB
  __shared__ float wgtl[64];  // [b][pos]
  const int t = threadIdx.x;
  const int tw = t >> 6, lo16 = t & 15, g = (t >> 4) & 3, l = t & 63;
  const int n0 = blockIdx.x * 32;
  const char* Wbig = wsb + B_WBIG;
  const char* WRp = wsb + B_WR;
  const char* CTXT = wsb + B_CTXT;
  const float* wsf = (const float*)wsb;
  const int bbase0 = lo16 * 1024 + g * 16;
  const int bbase1 = bbase0 + 16384;
  const int bswz = (lo16 & 7) << 4;
  const int swzq = (lo16 & 7) << 4;

#pragma unroll
  for (int r = 0; r < 2; ++r) {
    int chunk = r * 1024 + t;
    int prow = chunk >> 6, j = chunk & 63;
    const f32x4* gx = (const f32x4*)(x + (size_t)(n0 + prow) * 512 + j * 8);
    const f32x4* gy = (const f32x4*)(y + (size_t)(n0 + prow) * 512 + j * 8);
    f32x4 x0 = __builtin_nontemporal_load(gx);
    f32x4 x1 = __builtin_nontemporal_load(gx + 1);
    f32x4 y0 = __builtin_nontemporal_load(gy);
    f32x4 y1 = __builtin_nontemporal_load(gy + 1);
    int byte = (prow * 1024 + j * 16) ^ ((prow & 7) << 4);
    uint4 pk;
    pk.x = pack2(x0[0], x0[1]); pk.y = pack2(x0[2], x0[3]);
    pk.z = pack2(x1[0], x1[1]); pk.w = pack2(x1[2], x1[3]);
    *(uint4*)(Xl + byte) = pk;
    pk.x = pack2(y0[0], y0[1]); pk.y = pack2(y0[2], y0[3]);
    pk.z = pack2(y1[0], y1[1]); pk.w = pack2(y1[2], y1[3]);
    *(uint4*)(Yl + byte) = pk;
    int abase = prow * 2048 + j * 32;
    int aswz = (prow & 7) << 4;
    f32x4 a0 = 0.25f * (x0 + y0);
    f32x4 a1 = 0.25f * (x1 + y1);
    *(f32x4*)(ACCb + (abase ^ aswz)) = a0;
    *(f32x4*)(ACCb + ((abase + 16) ^ aswz)) = a1;
  }
  __syncthreads();

  f32x4 ax0p0 = {0,0,0,0}, ax0p1 = {0,0,0,0}, ay0p0 = {0,0,0,0}, ay0p1 = {0,0,0,0};
  f32x4 ax1p0 = {0,0,0,0}, ax1p1 = {0,0,0,0}, ay1p0 = {0,0,0,0}, ay1p1 = {0,0,0,0};
  {
    int t0 = tw * 2;
    const char* ap = Wbig + t0 * 16384 + l * 16;
    __builtin_amdgcn_s_setprio(1);
#pragma unroll
    for (int ks = 0; ks < 16; ++ks) {
      bf16x8 bx0 = *(const bf16x8*)(Xl + ((bbase0 + ks * 64) ^ bswz));
      bf16x8 bx1 = *(const bf16x8*)(Xl + ((bbase1 + ks * 64) ^ bswz));
      bf16x8 by0 = *(const bf16x8*)(Yl + ((bbase0 + ks * 64) ^ bswz));
      bf16x8 by1 = *(const bf16x8*)(Yl + ((bbase1 + ks * 64) ^ bswz));
      bf16x8 af0 = *(const bf16x8*)(ap + ks * 1024);
      bf16x8 af1 = *(const bf16x8*)(ap + 16384 + ks * 1024);
      ax0p0 = MFMA(af0, bx0, ax0p0); ax0p1 = MFMA(af0, bx1, ax0p1);
      ay0p0 = MFMA(af0, by0, ay0p0); ay0p1 = MFMA(af0, by1, ay0p1);
      ax1p0 = MFMA(af1, bx0, ax1p0); ax1p1 = MFMA(af1, bx1, ax1p1);
      ay1p0 = MFMA(af1, by0, ay1p0); ay1p1 = MFMA(af1, by1, ay1p1);
    }
    __builtin_amdgcn_s_setprio(0);
  }

  unsigned Qy0[4], Qy1[4];

  if (tw < 8) {
    int hh = tw;
    unsigned o[4];
    softmax_pack(ax0p0, ax1p0, bq, hh, g, o);
    {
      int base_q = lo16 * 512 + hh * 64 + g * 8;
      uint2 w0; w0.x = o[0]; w0.y = o[1];
      uint2 w1; w1.x = o[2]; w1.y = o[3];
      *(uint2*)(Ql + (base_q ^ swzq)) = w0;
      *(uint2*)(Ql + ((base_q + 32) ^ swzq)) = w1;
    }
    softmax_pack(ay0p0, ay1p0, bq, hh, g, Qy0);
    softmax_pack(ax0p1, ax1p1, bq, hh, g, o);
    {
      int base_q = lo16 * 512 + hh * 64 + g * 8;
      uint2 w0; w0.x = o[0]; w0.y = o[1];
      uint2 w1; w1.x = o[2]; w1.y = o[3];
      *(uint2*)(Ql + 8192 + (base_q ^ swzq)) = w0;
      *(uint2*)(Ql + 8192 + ((base_q + 32) ^ swzq)) = w1;
    }
    softmax_pack(ay0p1, ay1p1, bq, hh, g, Qy1);
  } else {
    int tile0 = tw * 2 - 16;
#pragma unroll
    for (int pt2 = 0; pt2 < 2; ++pt2) {
      int row = pt2 * 16 + lo16;
      int rsw = (row & 7) << 4;
#pragma unroll
      for (int half = 0; half < 2; ++half) {
        f32x4 axs = half ? (pt2 ? ax1p1 : ax1p0) : (pt2 ? ax0p1 : ax0p0);
        f32x4 ays = half ? (pt2 ? ay1p1 : ay1p0) : (pt2 ? ay0p1 : ay0p0);
        int ch4 = 64 + (tile0 + half) * 4 + g;
        int ab = (row * 2048 + ch4 * 16) ^ rsw;
        f32x4 cur = *(const f32x4*)(ACCb + ab);
        cur += 0.25f * (axs + ays);
        *(f32x4*)(ACCb + ab) = cur;
      }
    }
  }

  if (tw == 15) {
    f32x4 adxp0 = {0,0,0,0}, adxp1 = {0,0,0,0}, adyp0 = {0,0,0,0}, adyp1 = {0,0,0,0};
    const char* ap = Wbig + 32 * 16384 + l * 16;
#pragma unroll
    for (int ks = 0; ks < 16; ++ks) {
      bf16x8 bx0 = *(const bf16x8*)(Xl + ((bbase0 + ks * 64) ^ bswz));
      bf16x8 bx1 = *(const bf16x8*)(Xl + ((bbase1 + ks * 64) ^ bswz));
      bf16x8 by0 = *(const bf16x8*)(Yl + ((bbase0 + ks * 64) ^ bswz));
      bf16x8 by1 = *(const bf16x8*)(Yl + ((bbase1 + ks * 64) ^ bswz));
      bf16x8 af = *(const bf16x8*)(ap + ks * 1024);
      adxp0 = MFMA(af, bx0, adxp0); adxp1 = MFMA(af, bx1, adxp1);
      adyp0 = MFMA(af, by0, adyp0); adyp1 = MFMA(af, by1, adyp1);
    }
    if (g == 0) {
#pragma unroll
      for (int pt2 = 0; pt2 < 2; ++pt2) {
        int pos = n0 + pt2 * 16 + lo16;
        float base_gx = -1.f + 2.f * (float)pos / 32767.f;
#pragma unroll
        for (int b = 0; b < 2; ++b) {
          f32x4 ad = b ? (pt2 ? adyp1 : adyp0) : (pt2 ? adxp1 : adxp0);
          float d0 = ad[0] + wsf[(B_CONSTD / 4) + b * 2 + 0];
          float d1 = ad[1] + wsf[(B_CONSTD / 4) + b * 2 + 1];
          float gxv = base_gx + d0;
          float gyv = -1.f + d1;
          float ix = gxv * 0.5f, iy = gyv * 0.5f;
          float wx = fminf(fmaxf(1.f - fabsf(ix), 0.f), 1.f);
          float wy = fminf(fmaxf(1.f - fabsf(iy), 0.f), 1.f);
          wgtl[b * 32 + pt2 * 16 + lo16] = wx * wy;
        }
      }
    }
  }

  if (tw < 8) {
    int hh = tw;
#pragma unroll
    for (int pt2 = 0; pt2 < 2; ++pt2) {
      unsigned char* Qs = Ql + pt2 * 8192;
      const unsigned* Qy = pt2 ? Qy1 : Qy0;
      f32x4 at0 = {0,0,0,0}, at1 = {0,0,0,0};
      {
        bf16x8 qf = *(const bf16x8*)(Qs + ((lo16 * 512 + hh * 64 + g * 16) ^ swzq));
        const char* cp = CTXT + (0 * 8 + hh) * 2048 + l * 16;
        bf16x8 c0 = *(const bf16x8*)(cp);
        bf16x8 c1 = *(const bf16x8*)(cp + 1024);
        at0 = MFMA(c0, qf, at0);
        at1 = MFMA(c1, qf, at1);
      }
      {
        int base_q = lo16 * 512 + hh * 64 + g * 8;
        uint2 w0; w0.x = Qy[0]; w0.y = Qy[1];
        uint2 w1; w1.x = Qy[2]; w1.y = Qy[3];
        *(uint2*)(Qs + (base_q ^ swzq)) = w0;
        *(uint2*)(Qs + ((base_q + 32) ^ swzq)) = w1;
      }
      {
        bf16x8 qf = *(const bf16x8*)(Qs + ((lo16 * 512 + hh * 64 + g * 16) ^ swzq));
        const char* cp = CTXT + (1 * 8 + hh) * 2048 + l * 16;
        bf16x8 c0 = *(const bf16x8*)(cp);
        bf16x8 c1 = *(const bf16x8*)(cp + 1024);
        at0 = MFMA(c0, qf, at0);
        at1 = MFMA(c1, qf, at1);
      }
#pragma unroll
      for (int m = 0; m < 2; ++m) {
        f32x4 v = m ? at1 : at0;
        uint2 wv;
        wv.x = pack2(v[0], v[1]); wv.y = pack2(v[2], v[3]);
        int byte = (lo16 * 512 + hh * 64 + m * 32 + g * 8) ^ swzq;
        *(uint2*)(Qs + byte) = wv;
      }
    }
  }
  __syncthreads();

  {
    int T0 = tw * 2;
    f32x4 r0p0 = {0,0,0,0}, r0p1 = {0,0,0,0}, r1p0 = {0,0,0,0}, r1p1 = {0,0,0,0};
    const char* ap = WRp + T0 * 8192 + l * 16;
    __builtin_amdgcn_s_setprio(1);
#pragma unroll
    for (int ks = 0; ks < 8; ++ks) {
      bf16x8 br0 = *(const bf16x8*)(Ql + ((lo16 * 512 + g * 16 + ks * 64) ^ swzq));
      bf16x8 br1 = *(const bf16x8*)(Ql + 8192 + ((lo16 * 512 + g * 16 + ks * 64) ^ swzq));
      bf16x8 a0 = *(const bf16x8*)(ap + ks * 1024);
      bf16x8 a1 = *(const bf16x8*)(ap + 8192 + ks * 1024);
      r0p0 = MFMA(a0, br0, r0p0); r0p1 = MFMA(a0, br1, r0p1);
      r1p0 = MFMA(a1, br0, r1p0); r1p1 = MFMA(a1, br1, r1p1);
    }
    __builtin_amdgcn_s_setprio(0);
#pragma unroll
    for (int pt2 = 0; pt2 < 2; ++pt2) {
      int row = pt2 * 16 + lo16;
      int rsw = (row & 7) << 4;
#pragma unroll
      for (int half = 0; half < 2; ++half) {
        f32x4 rr = half ? (pt2 ? r1p1 : r1p0) : (pt2 ? r0p1 : r0p0);
        int ch4 = (T0 + half) * 4 + g;
        int ab = (row * 2048 + ch4 * 16) ^ rsw;
        f32x4 cur = *(const f32x4*)(ACCb + ab);
        cur += 0.25f * rr;
        *(f32x4*)(ACCb + ab) = cur;
      }
    }
  }
  __syncthreads();

  const float* bo = wsf + (B_BIASO / 4);
#pragma unroll
  for (int i = 0; i < 4; ++i) {
    int idx = i * 1024 + t;
    int pos = idx >> 7, c4 = idx & 127;
    int ab = (pos * 2048 + c4 * 16) ^ ((pos & 7) << 4);
    f32x4 acc = *(const f32x4*)(ACCb + ab);
    f32x4 bb = *(const f32x4*)(bo + c4 * 4);
    if (c4 < 64) {
      f32x4 h20 = *(const f32x4*)(wsf + (B_HIGH2 / 4) + c4 * 4);
      f32x4 h21 = *(const f32x4*)(wsf + (B_HIGH2 / 4) + 256 + c4 * 4);
      float wg0 = wgtl[pos], wg1 = wgtl[32 + pos];
      acc += (0.25f * wg0) * h20 + (0.25f * wg1) * h21;
    }
    acc += bb;
    __builtin_nontemporal_store(acc, (f32x4*)(out + (size_t)(n0 + pos) * 512 + c4 * 4));
  }
}

extern "C" void kernel_launch(void* const* d_in, const int* in_sizes, int n_in,
                              void* d_out, int out_size, void* d_ws, size_t ws_size,
                              hipStream_t stream) {
  const float* x = (const float*)d_in[0];
  const float* y = (const float*)d_in[1];
  const float* ea_wk = (const float*)d_in[2];
  const float* ea_bk = (const float*)d_in[3];
  const float* ea_wq = (const float*)d_in[4];
  const float* ea_bq = (const float*)d_in[5];
  const float* ea_wv = (const float*)d_in[6];
  const float* ea_bv = (const float*)d_in[7];
  const float* ea_wr = (const float*)d_in[8];
  const float* ea_br = (const float*)d_in[9];
  const float* pool_w1 = (const float*)d_in[10];
  const float* pool_bn1 = (const float*)d_in[11];
  const float* pool_w2 = (const float*)d_in[12];
  const float* pool_bn2 = (const float*)d_in[13];
  const float* adapt_w1 = (const float*)d_in[14];
  const float* adapt_bn1 = (const float*)d_in[15];
  const float* adapt_w2 = (const float*)d_in[16];
  const float* adapt_bn2 = (const float*)d_in[17];
  const float* delta_w1 = (const float*)d_in[18];
  const float* delta_bn1 = (const float*)d_in[19];
  const float* delta_w2 = (const float*)d_in[20];
  char* ws = (char*)d_ws;
  float* out = (float*)d_out;

  kFuse1<<<2176, 512, 0, stream>>>(adapt_w1, adapt_bn1, adapt_w2, adapt_bn2,
                                   ea_wq, ea_wk, ea_wv, ea_wr, pool_w1, pool_w2,
                                   delta_w1, ws);
  kW2<<<8, 512, 0, stream>>>(delta_w1, delta_bn1, delta_w2, ws);
  kPackB<<<272, 512, 0, stream>>>(ws);
  k1_reduce<<<1024, 1024, 0, stream>>>(x, y, ea_bk, ea_bv, ws, out);
  k1b<<<224, 512, 0, stream>>>(out, ws);
  k2_finalize<<<17, 1024, 0, stream>>>(pool_bn1, pool_bn2, delta_bn1, delta_w2, ea_br, ws);
  k3_main<<<1024, 1024, 0, stream>>>(x, y, ea_bq, ws, out);
}